// Round 16
// baseline (384.792 us; speedup 1.0000x reference)
//
#include <hip/hip_runtime.h>
#include <hip/hip_bf16.h>
#include <hip/hip_cooperative_groups.h>

namespace cg = cooperative_groups;

// MultiLayerGATv2 — Round 16: CSR build fused into ONE cooperative kernel
// (hist+epos / block sums / rowptr scan / scatter, grid.sync between phases).
// gat_ln + GEMMs unchanged from R15 (measured at structural floors).
// Journal: R11=188 -> R14=183 (gat_ln 44.4) -> R15=183.3 (gat_ln 43.5).

#define NN 50000
#define EE 800000
#define EP (EE + NN)
#define IN_DIM 256
#define HID 128
#define SLOPE 0.2f
#define LN_EPS 1e-5f
#define NB 196          // ceil(NN / 256)
#define CSRB 512        // cooperative grid blocks (co-resident: 2/CU)
#define L2E 1.4426950408889634f

typedef short s8v __attribute__((ext_vector_type(8)));   // 8 bf16 (4 VGPR)
typedef float f4v __attribute__((ext_vector_type(4)));   // MFMA C/D

__device__ __forceinline__ float u2f(unsigned int u) {
    union { unsigned int i; float f; } c; c.i = u; return c.f;
}
__device__ __forceinline__ unsigned short f2bf(float f) {
    union { float f; unsigned int i; } c; c.f = f;
    unsigned int r = (c.i + 0x7fffu + ((c.i >> 16) & 1u)) >> 16;   // RNE
    return (unsigned short)r;
}
__device__ __forceinline__ void unpack8(const uint4 raw, float* m) {
    m[0] = u2f(raw.x << 16); m[1] = u2f(raw.x & 0xffff0000u);
    m[2] = u2f(raw.y << 16); m[3] = u2f(raw.y & 0xffff0000u);
    m[4] = u2f(raw.z << 16); m[5] = u2f(raw.z & 0xffff0000u);
    m[6] = u2f(raw.w << 16); m[7] = u2f(raw.w & 0xffff0000u);
}
// sum over the 4 lanes of a quad via DPP quad_perm (no LDS pipe)
__device__ __forceinline__ float quad_sum(float v) {
    v += __int_as_float(__builtin_amdgcn_update_dpp(
            0, __float_as_int(v), 0xB1 /*[1,0,3,2]*/, 0xF, 0xF, true));
    v += __int_as_float(__builtin_amdgcn_update_dpp(
            0, __float_as_int(v), 0x4E /*[2,3,0,1]*/, 0xF, 0xF, true));
    return v;
}

// ---------------- weight prep ----------------
__global__ void prep_weights(const float* __restrict__ Win,
                             const float* __restrict__ Wl,
                             const float* __restrict__ Wr,
                             float4* __restrict__ wp) {
    const int sid = blockIdx.x * 256 + threadIdx.x;    // grid 48*256 = 12288
    const float* W;
    int slot;
    if (sid < 4096) { W = Win; slot = sid; }
    else {
        const int m = (sid - 4096) >> 11;
        slot = (sid - 4096) & 2047;
        W = (m == 0) ? Wl : (m == 1) ? Wr : (m == 2) ? (Wl + 16384) : (Wr + 16384);
    }
    const int n = slot & 127;
    const int kbase = (slot >> 9) * 32 + ((slot >> 7) & 3) * 8;
    unsigned short o[8];
#pragma unroll
    for (int j = 0; j < 8; j++) o[j] = f2bf(W[(size_t)(kbase + j) * 128 + n]);
    wp[sid] = *(const float4*)o;
}

// ---------------- fused CSR build (cooperative) ----------------
// phase 0: zero cnt; phase 1: hist + epos; phase 2: block sums;
// phase 3: rowptr scan; phase 4: scatter pre-shifted byte offsets.
__global__ void csr_build(const int* __restrict__ ei,
                          int* __restrict__ cnt,
                          unsigned short* __restrict__ epos,
                          int* __restrict__ bsum,
                          int* __restrict__ rowptr,
                          int* __restrict__ esrcb) {
    cg::grid_group grid = cg::this_grid();
    const int tid = threadIdx.x;
    const int gtid = blockIdx.x * 256 + tid;
    const int gstride = CSRB * 256;
    const int lane = tid & 63, wv = tid >> 6;

    // phase 0: zero cnt
    for (int i = gtid; i < NN; i += gstride) cnt[i] = 0;
    grid.sync();

    // phase 1: histogram + per-edge position capture
    for (int e = gtid; e < EP; e += gstride) {
        const int d = (e < EE) ? ei[EE + e] : (e - EE);
        epos[e] = (unsigned short)atomicAdd(&cnt[d], 1);
    }
    grid.sync();

    // phase 2: per-256-chunk totals (blocks 0..NB-1)
    if (blockIdx.x < NB) {
        const int i = blockIdx.x * 256 + tid;
        int v = (i < NN) ? cnt[i] : 0;
#pragma unroll
        for (int off = 1; off < 64; off <<= 1) v += __shfl_xor(v, off);
        __shared__ int ws0[4];
        if (lane == 0) ws0[wv] = v;
        __syncthreads();
        if (tid == 0) bsum[blockIdx.x] = ws0[0] + ws0[1] + ws0[2] + ws0[3];
    }
    grid.sync();

    // phase 3: rowptr = exclusive scan (blocks 0..NB-1, self-computed prefix)
    if (blockIdx.x < NB) {
        __shared__ int ws[4];
        __shared__ int pref;
        {
            int v = (tid < (int)blockIdx.x && tid < NB) ? bsum[tid] : 0;
#pragma unroll
            for (int off = 1; off < 64; off <<= 1) v += __shfl_xor(v, off);
            if (lane == 0) ws[wv] = v;
            __syncthreads();
            if (tid == 0) pref = ws[0] + ws[1] + ws[2] + ws[3];
            __syncthreads();
        }
        const int i = blockIdx.x * 256 + tid;
        const int v = (i < NN) ? cnt[i] : 0;
        int s = v;
#pragma unroll
        for (int off = 1; off < 64; off <<= 1) {
            const int u = __shfl_up(s, off);
            if (lane >= off) s += u;
        }
        __shared__ int wt[4];
        if (lane == 63) wt[wv] = s;
        __syncthreads();
        int add = pref;
        for (int w = 0; w < wv; w++) add += wt[w];
        const int excl = s + add - v;
        if (i < NN) rowptr[i] = excl;
        if (i == NN - 1) rowptr[NN] = excl + v;   // == EP
    }
    grid.sync();

    // phase 4: atomic-free scatter of pre-shifted byte offsets
    for (int e = gtid; e < EP; e += gstride) {
        int s, d;
        if (e < EE) { s = ei[e]; d = ei[EE + e]; }
        else        { s = d = e - EE; }
        esrcb[rowptr[d] + epos[e]] = s * (HID * 2);
    }
}

// ---------------- input GEMM + bias + LN + ReLU, MFMA -> bf16 h --------------
__global__ __launch_bounds__(256) void gemm_in_mfma(
        const float* __restrict__ x,
        const float4* __restrict__ wp,
        const float* __restrict__ bin,
        const float* __restrict__ g,
        const float* __restrict__ bb,
        unsigned short* __restrict__ hb) {
    __shared__ s8v wlds[4096];                // 64 KB
    const int tid = threadIdx.x;
    const int wv = tid >> 6, lane = tid & 63;
    const int l15 = lane & 15, kseg = lane >> 4;
    const int row0 = blockIdx.x * 64 + wv * 16;
    const int arow = row0 + l15;
    const int r = (arow < NN) ? arow : 0;

    s8v afrag[8];
#pragma unroll
    for (int ks = 0; ks < 8; ks++) {
        const float* ap = x + (size_t)r * IN_DIM + ks * 32 + kseg * 8;
        const float4 a0 = *(const float4*)ap;
        const float4 a1 = *(const float4*)(ap + 4);
        unsigned short t[8] = { f2bf(a0.x), f2bf(a0.y), f2bf(a0.z), f2bf(a0.w),
                                f2bf(a1.x), f2bf(a1.y), f2bf(a1.z), f2bf(a1.w) };
        afrag[ks] = *(const s8v*)t;
    }

#pragma unroll
    for (int i = 0; i < 16; i++) {
        const int idx = i * 256 + tid;
        ((float4*)wlds)[idx] = wp[idx];
    }
    __syncthreads();

    f4v acc[8];
#pragma unroll
    for (int nb = 0; nb < 8; nb++) acc[nb] = (f4v){0.f, 0.f, 0.f, 0.f};
#pragma unroll
    for (int ks = 0; ks < 8; ks++) {
#pragma unroll
        for (int nb = 0; nb < 8; nb++) {
            const s8v bfrag = wlds[(ks * 4 + kseg) * 128 + nb * 16 + l15];
            acc[nb] = __builtin_amdgcn_mfma_f32_16x16x32_bf16(afrag[ks], bfrag, acc[nb], 0, 0, 0);
        }
    }

    float binv[8], gv[8], bbv[8];
#pragma unroll
    for (int nb = 0; nb < 8; nb++) {
        const int col = nb * 16 + l15;
        binv[nb] = bin[col]; gv[nb] = g[col]; bbv[nb] = bb[col];
    }
    float s1[4] = {0.f, 0.f, 0.f, 0.f}, s2[4] = {0.f, 0.f, 0.f, 0.f};
#pragma unroll
    for (int nb = 0; nb < 8; nb++)
#pragma unroll
        for (int reg = 0; reg < 4; reg++) {
            const float t = acc[nb][reg] + binv[nb];
            acc[nb][reg] = t;
            s1[reg] += t; s2[reg] += t * t;
        }
#pragma unroll
    for (int off = 1; off < 16; off <<= 1)
#pragma unroll
        for (int reg = 0; reg < 4; reg++) {
            s1[reg] += __shfl_xor(s1[reg], off);
            s2[reg] += __shfl_xor(s2[reg], off);
        }
    float mu[4], rstd[4];
#pragma unroll
    for (int reg = 0; reg < 4; reg++) {
        mu[reg] = s1[reg] / (float)HID;
        rstd[reg] = rsqrtf(s2[reg] / (float)HID - mu[reg] * mu[reg] + LN_EPS);
    }
    const int rbase = row0 + 4 * kseg;
#pragma unroll
    for (int reg = 0; reg < 4; reg++) {
        const int grow = rbase + reg;
        if (grow >= NN) continue;
#pragma unroll
        for (int nb = 0; nb < 8; nb++) {
            const int col = nb * 16 + l15;
            float v = (acc[nb][reg] - mu[reg]) * rstd[reg] * gv[nb] + bbv[nb];
            hb[(size_t)grow * HID + col] = f2bf(fmaxf(v, 0.f));
        }
    }
}

// ---------------- dual GEMM (h@Wl -> xl bf16, h@Wr -> xr bf16), MFMA ---------
__global__ __launch_bounds__(256) void gemm_xlxr_mfma(
        const unsigned short* __restrict__ hb,
        const float4* __restrict__ wp,
        unsigned short* __restrict__ xl,
        unsigned short* __restrict__ xrb) {
    __shared__ s8v wlds[4096];                // 64 KB
    const int tid = threadIdx.x;
    const int wv = tid >> 6, lane = tid & 63;
    const int l15 = lane & 15, kseg = lane >> 4;
    const int row0 = blockIdx.x * 64 + wv * 16;
    const int arow = row0 + l15;
    const int r = (arow < NN) ? arow : 0;

    s8v afrag[4];
#pragma unroll
    for (int ks = 0; ks < 4; ks++)
        afrag[ks] = *(const s8v*)(hb + (size_t)r * HID + ks * 32 + kseg * 8);

#pragma unroll
    for (int i = 0; i < 16; i++) {
        const int idx = i * 256 + tid;
        ((float4*)wlds)[idx] = wp[idx];
    }
    __syncthreads();

    f4v accL[8], accR[8];
#pragma unroll
    for (int nb = 0; nb < 8; nb++) {
        accL[nb] = (f4v){0.f, 0.f, 0.f, 0.f};
        accR[nb] = (f4v){0.f, 0.f, 0.f, 0.f};
    }
#pragma unroll
    for (int ks = 0; ks < 4; ks++) {
#pragma unroll
        for (int nb = 0; nb < 8; nb++) {
            const s8v bL = wlds[(ks * 4 + kseg) * 128 + nb * 16 + l15];
            accL[nb] = __builtin_amdgcn_mfma_f32_16x16x32_bf16(afrag[ks], bL, accL[nb], 0, 0, 0);
            const s8v bR = wlds[2048 + (ks * 4 + kseg) * 128 + nb * 16 + l15];
            accR[nb] = __builtin_amdgcn_mfma_f32_16x16x32_bf16(afrag[ks], bR, accR[nb], 0, 0, 0);
        }
    }

    const int rbase = row0 + 4 * kseg;
#pragma unroll
    for (int reg = 0; reg < 4; reg++) {
        const int grow = rbase + reg;
        if (grow >= NN) continue;
#pragma unroll
        for (int nb = 0; nb < 8; nb++) {
            const int col = nb * 16 + l15;
            xl[(size_t)grow * HID + col]  = f2bf(accL[nb][reg]);
            xrb[(size_t)grow * HID + col] = f2bf(accR[nb][reg]);
        }
    }
}

// ---------------- fused GAT conv + LN + ELU + residual ----------------
// 4 nodes/wave: 16-lane group per node, lane holds 8 features.
// 4-deep gather pipeline + double-buffered offset refill + DPP quad reduce.
__global__ __launch_bounds__(256) void gat_ln(
        const unsigned short* __restrict__ xl,
        const unsigned short* __restrict__ xrb,
        const float* __restrict__ att,
        const int* __restrict__ rowptr,
        const int* __restrict__ esrcb,
        const float* __restrict__ g,
        const float* __restrict__ b,
        const unsigned short* __restrict__ hres,   // bf16 residual
        float* __restrict__ dest,                  // f32 out (last layer) or null
        unsigned short* __restrict__ destb) {      // bf16 h_next or null
    const int tid = threadIdx.x;
    const int lane = tid & 63;
    const int wv = tid >> 6;
    const int l16 = lane & 15;
    const int node = blockIdx.x * 16 + wv * 4 + (lane >> 4);   // grid*16 == NN
    const int f0 = l16 * 8;

    float xrv[8], a06[8], a04[8];
    {
        const uint4 xraw = *(const uint4*)(xrb + (size_t)node * HID + f0);
        unpack8(xraw, xrv);
        const float4 t0 = *(const float4*)(att + f0);
        const float4 t1 = *(const float4*)(att + f0 + 4);
        float av[8] = { t0.x, t0.y, t0.z, t0.w, t1.x, t1.y, t1.z, t1.w };
#pragma unroll
        for (int j = 0; j < 8; j++) {
            a06[j] = 0.6f * L2E * av[j];
            a04[j] = 0.4f * L2E * av[j];
        }
    }
    // hoist epilogue constants (latency overlap with edge loop)
    float gv[8], bv[8], hv[8];
    {
        const float4 g0 = *(const float4*)(g + f0);
        const float4 g1 = *(const float4*)(g + f0 + 4);
        gv[0]=g0.x; gv[1]=g0.y; gv[2]=g0.z; gv[3]=g0.w;
        gv[4]=g1.x; gv[5]=g1.y; gv[6]=g1.z; gv[7]=g1.w;
        const float4 b0 = *(const float4*)(b + f0);
        const float4 b1 = *(const float4*)(b + f0 + 4);
        bv[0]=b0.x; bv[1]=b0.y; bv[2]=b0.z; bv[3]=b0.w;
        bv[4]=b1.x; bv[5]=b1.y; bv[6]=b1.z; bv[7]=b1.w;
        const uint4 hraw = *(const uint4*)(hres + (size_t)node * HID + f0);
        unpack8(hraw, hv);
    }
    const int beg = rowptr[node];
    const int deg = rowptr[node + 1] - beg;            // >= 1
    int dmax = deg;
    dmax = max(dmax, __shfl_xor(dmax, 16));
    dmax = max(dmax, __shfl_xor(dmax, 32));            // max over the wave's 4 nodes

    const char* xlbase = (const char*)xl + f0 * 2;     // lane feature base (bytes)
    const int gb = lane & 48;                          // shfl base of this group

    float acc[8];
#pragma unroll
    for (int j = 0; j < 8; j++) acc[j] = 0.f;
    float z = 0.f;

    // double-buffered 16-deep offset windows (prefetched one window ahead)
    int sb_cur = (l16 < deg)      ? esrcb[beg + l16]      : 0;
    int sb_nxt = (16 + l16 < deg) ? esrcb[beg + 16 + l16] : 0;

#define PROCR(RAW, VALID) do {                                              \
        float m[8];                                                         \
        unpack8((RAW), m);                                                  \
        float v = 0.f;                                                      \
        _Pragma("unroll")                                                   \
        for (int j = 0; j < 8; j++) {                                       \
            const float tt = m[j] + xrv[j];                                 \
            v += tt * a06[j] + fabsf(tt) * a04[j];                          \
        }                                                                   \
        v = quad_sum(v);                /* head = 4 lanes, DPP */           \
        const float a = (VALID) ? __builtin_amdgcn_exp2f(v) : 0.f;          \
        z += a;                                                             \
        _Pragma("unroll")                                                   \
        for (int j = 0; j < 8; j++) acc[j] = fmaf(a, m[j], acc[j]);         \
    } while (0)

    for (int t = 0; t < dmax; t += 4) {
        if ((t & 15) == 0 && t) {                      // rotate windows
            sb_cur = sb_nxt;
            sb_nxt = (t + 16 + l16 < deg) ? esrcb[beg + t + 16 + l16] : 0;
        }
        const int o0 = __shfl(sb_cur, gb | ((t + 0) & 15));
        const int o1 = __shfl(sb_cur, gb | ((t + 1) & 15));
        const int o2 = __shfl(sb_cur, gb | ((t + 2) & 15));
        const int o3 = __shfl(sb_cur, gb | ((t + 3) & 15));
        // 4 independent loads in flight
        const uint4 r0 = *(const uint4*)(xlbase + o0);
        const uint4 r1 = *(const uint4*)(xlbase + o1);
        const uint4 r2 = *(const uint4*)(xlbase + o2);
        const uint4 r3 = *(const uint4*)(xlbase + o3);
        PROCR(r0, t + 0 < deg);
        PROCR(r1, t + 1 < deg);
        PROCR(r2, t + 2 < deg);
        PROCR(r3, t + 3 < deg);
    }
#undef PROCR

    // epilogue: alpha normalize + LN + ELU + residual (group-local)
    const float inv = 1.f / z;
    float o[8];
    float s1 = 0.f, s2 = 0.f;
#pragma unroll
    for (int j = 0; j < 8; j++) {
        o[j] = acc[j] * inv;
        s1 += o[j];
        s2 = fmaf(o[j], o[j], s2);
    }
#pragma unroll
    for (int off = 1; off < 16; off <<= 1) {
        s1 += __shfl_xor(s1, off);
        s2 += __shfl_xor(s2, off);
    }
    const float mu = s1 / (float)HID;
    const float rstd = rsqrtf(s2 / (float)HID - mu * mu + LN_EPS);

    float res[8];
#pragma unroll
    for (int j = 0; j < 8; j++) {
        float n = (o[j] - mu) * rstd * gv[j] + bv[j];
        n = (n > 0.f) ? n : (__builtin_amdgcn_exp2f(n * L2E) - 1.f);   // ELU
        res[j] = hv[j] + n;
    }
    if (dest) {
        float* dp = dest + (size_t)node * HID + f0;
        *(float4*)dp       = (float4){res[0], res[1], res[2], res[3]};
        *(float4*)(dp + 4) = (float4){res[4], res[5], res[6], res[7]};
    }
    if (destb) {
        unsigned short o16[8];
#pragma unroll
        for (int j = 0; j < 8; j++) o16[j] = f2bf(res[j]);
        *(uint4*)(destb + (size_t)node * HID + f0) = *(const uint4*)o16;
    }
}

extern "C" void kernel_launch(void* const* d_in, const int* in_sizes, int n_in,
                              void* d_out, int out_size, void* d_ws, size_t ws_size,
                              hipStream_t stream) {
    const float* x       = (const float*)d_in[0];
    const float* W_in    = (const float*)d_in[1];
    const float* b_in    = (const float*)d_in[2];
    const float* ln_in_g = (const float*)d_in[3];
    const float* ln_in_b = (const float*)d_in[4];
    const float* Wl      = (const float*)d_in[5];
    const float* Wr      = (const float*)d_in[6];
    const float* att     = (const float*)d_in[7];
    const float* ln_g    = (const float*)d_in[8];
    const float* ln_b    = (const float*)d_in[9];
    const int*   ei      = (const int*)d_in[10];
    float* out = (float*)d_out;

    unsigned short* hb  = (unsigned short*)d_ws;               // NN*128 bf16
    unsigned short* hb2 = hb  + (size_t)NN * HID;              // NN*128 bf16
    unsigned short* xlb = hb2 + (size_t)NN * HID;              // NN*128 bf16
    unsigned short* xrb = xlb + (size_t)NN * HID;              // NN*128 bf16
    float4* wp = (float4*)(xrb + (size_t)NN * HID);            // 12288 slots
    int* cnt    = (int*)(wp + 12288);                          // NN
    int* rowptr = cnt + NN;                                    // NN+1
    int* bsum   = rowptr + (NN + 1);                           // NB
    int* esrcb  = bsum + NB;                                   // EP i32 (byte offs)
    unsigned short* epos = (unsigned short*)(esrcb + EP);      // EP u16

    prep_weights<<<48, 256, 0, stream>>>(W_in, Wl, Wr, wp);

    {
        void* args[] = { (void*)&ei, (void*)&cnt, (void*)&epos,
                         (void*)&bsum, (void*)&rowptr, (void*)&esrcb };
        (void)hipLaunchCooperativeKernel((void*)csr_build, dim3(CSRB), dim3(256),
                                         args, 0, stream);
    }

    const int mblocks = (NN + 63) / 64;
    gemm_in_mfma<<<mblocks, 256, 0, stream>>>(x, wp, b_in, ln_in_g, ln_in_b, hb);

    for (int l = 0; l < 2; l++) {
        const unsigned short* hsrc = (l == 0) ? hb : hb2;
        gemm_xlxr_mfma<<<mblocks, 256, 0, stream>>>(hsrc, wp + 4096 + l * 4096, xlb, xrb);
        gat_ln<<<NN / 16, 256, 0, stream>>>(xlb, xrb, att + (size_t)l * HID,
                                            rowptr, esrcb,
                                            ln_g + (size_t)l * HID,
                                            ln_b + (size_t)l * HID,
                                            hsrc,
                                            (l == 1) ? out : (float*)nullptr,
                                            (l == 0) ? hb2 : (unsigned short*)nullptr);
    }
}

// Round 17
// 182.849 us; speedup vs baseline: 2.1044x; 2.1044x over previous
//
#include <hip/hip_runtime.h>
#include <hip/hip_bf16.h>

// MultiLayerGATv2 — Round 17: REVERT to R15 (best measured: 183.2us).
// R16's cooperative CSR fusion regressed (grid.sync ~200us on 8-XCD MI355X).
// Journal: R11=188 -> R14=183.2 (gat_ln 44.4) -> R15=183.3 (gat_ln 43.5)
//          -> R16=385 (coop REVERTED).
// Measured floors: gat_ln ~43.5us (L3 random-gather ~5TB/s, warm==cold);
// gemm_xlxr ~13us (stream floor); gemm_in ~17us (fp32 x read);
// CSR chain ~35us (850K random atomic RMW). Structural alternatives all
// tested & worse: degree-sort, wave/node, 8-deep, coop-fusion.

#define NN 50000
#define EE 800000
#define EP (EE + NN)
#define IN_DIM 256
#define HID 128
#define SLOPE 0.2f
#define LN_EPS 1e-5f
#define NB 196          // ceil(50000 / 256)
#define L2E 1.4426950408889634f

typedef short s8v __attribute__((ext_vector_type(8)));   // 8 bf16 (4 VGPR)
typedef float f4v __attribute__((ext_vector_type(4)));   // MFMA C/D

__device__ __forceinline__ float u2f(unsigned int u) {
    union { unsigned int i; float f; } c; c.i = u; return c.f;
}
__device__ __forceinline__ unsigned short f2bf(float f) {
    union { float f; unsigned int i; } c; c.f = f;
    unsigned int r = (c.i + 0x7fffu + ((c.i >> 16) & 1u)) >> 16;   // RNE
    return (unsigned short)r;
}
__device__ __forceinline__ void unpack8(const uint4 raw, float* m) {
    m[0] = u2f(raw.x << 16); m[1] = u2f(raw.x & 0xffff0000u);
    m[2] = u2f(raw.y << 16); m[3] = u2f(raw.y & 0xffff0000u);
    m[4] = u2f(raw.z << 16); m[5] = u2f(raw.z & 0xffff0000u);
    m[6] = u2f(raw.w << 16); m[7] = u2f(raw.w & 0xffff0000u);
}
// sum over the 4 lanes of a quad via DPP quad_perm (no LDS pipe)
__device__ __forceinline__ float quad_sum(float v) {
    v += __int_as_float(__builtin_amdgcn_update_dpp(
            0, __float_as_int(v), 0xB1 /*[1,0,3,2]*/, 0xF, 0xF, true));
    v += __int_as_float(__builtin_amdgcn_update_dpp(
            0, __float_as_int(v), 0x4E /*[2,3,0,1]*/, 0xF, 0xF, true));
    return v;
}

// ---------------- weight prep + cnt zeroing ----------------
__global__ void prep_weights(const float* __restrict__ Win,
                             const float* __restrict__ Wl,
                             const float* __restrict__ Wr,
                             float4* __restrict__ wp,
                             int* __restrict__ cnt) {
    const int sid = blockIdx.x * 256 + threadIdx.x;    // grid 48*256 = 12288
    for (int i = sid; i < NN; i += 12288) cnt[i] = 0;

    const float* W;
    int slot;
    if (sid < 4096) { W = Win; slot = sid; }
    else {
        const int m = (sid - 4096) >> 11;
        slot = (sid - 4096) & 2047;
        W = (m == 0) ? Wl : (m == 1) ? Wr : (m == 2) ? (Wl + 16384) : (Wr + 16384);
    }
    const int n = slot & 127;
    const int kbase = (slot >> 9) * 32 + ((slot >> 7) & 3) * 8;
    unsigned short o[8];
#pragma unroll
    for (int j = 0; j < 8; j++) o[j] = f2bf(W[(size_t)(kbase + j) * 128 + n]);
    wp[sid] = *(const float4*)o;
}

// ---------------- input GEMM + bias + LN + ReLU, MFMA -> bf16 h --------------
__global__ __launch_bounds__(256) void gemm_in_mfma(
        const float* __restrict__ x,
        const float4* __restrict__ wp,
        const float* __restrict__ bin,
        const float* __restrict__ g,
        const float* __restrict__ bb,
        unsigned short* __restrict__ hb) {
    __shared__ s8v wlds[4096];                // 64 KB
    const int tid = threadIdx.x;
    const int wv = tid >> 6, lane = tid & 63;
    const int l15 = lane & 15, kseg = lane >> 4;
    const int row0 = blockIdx.x * 64 + wv * 16;
    const int arow = row0 + l15;
    const int r = (arow < NN) ? arow : 0;

    s8v afrag[8];
#pragma unroll
    for (int ks = 0; ks < 8; ks++) {
        const float* ap = x + (size_t)r * IN_DIM + ks * 32 + kseg * 8;
        const float4 a0 = *(const float4*)ap;
        const float4 a1 = *(const float4*)(ap + 4);
        unsigned short t[8] = { f2bf(a0.x), f2bf(a0.y), f2bf(a0.z), f2bf(a0.w),
                                f2bf(a1.x), f2bf(a1.y), f2bf(a1.z), f2bf(a1.w) };
        afrag[ks] = *(const s8v*)t;
    }

#pragma unroll
    for (int i = 0; i < 16; i++) {
        const int idx = i * 256 + tid;
        ((float4*)wlds)[idx] = wp[idx];
    }
    __syncthreads();

    f4v acc[8];
#pragma unroll
    for (int nb = 0; nb < 8; nb++) acc[nb] = (f4v){0.f, 0.f, 0.f, 0.f};
#pragma unroll
    for (int ks = 0; ks < 8; ks++) {
#pragma unroll
        for (int nb = 0; nb < 8; nb++) {
            const s8v bfrag = wlds[(ks * 4 + kseg) * 128 + nb * 16 + l15];
            acc[nb] = __builtin_amdgcn_mfma_f32_16x16x32_bf16(afrag[ks], bfrag, acc[nb], 0, 0, 0);
        }
    }

    float binv[8], gv[8], bbv[8];
#pragma unroll
    for (int nb = 0; nb < 8; nb++) {
        const int col = nb * 16 + l15;
        binv[nb] = bin[col]; gv[nb] = g[col]; bbv[nb] = bb[col];
    }
    float s1[4] = {0.f, 0.f, 0.f, 0.f}, s2[4] = {0.f, 0.f, 0.f, 0.f};
#pragma unroll
    for (int nb = 0; nb < 8; nb++)
#pragma unroll
        for (int reg = 0; reg < 4; reg++) {
            const float t = acc[nb][reg] + binv[nb];
            acc[nb][reg] = t;
            s1[reg] += t; s2[reg] += t * t;
        }
#pragma unroll
    for (int off = 1; off < 16; off <<= 1)
#pragma unroll
        for (int reg = 0; reg < 4; reg++) {
            s1[reg] += __shfl_xor(s1[reg], off);
            s2[reg] += __shfl_xor(s2[reg], off);
        }
    float mu[4], rstd[4];
#pragma unroll
    for (int reg = 0; reg < 4; reg++) {
        mu[reg] = s1[reg] / (float)HID;
        rstd[reg] = rsqrtf(s2[reg] / (float)HID - mu[reg] * mu[reg] + LN_EPS);
    }
    const int rbase = row0 + 4 * kseg;
#pragma unroll
    for (int reg = 0; reg < 4; reg++) {
        const int grow = rbase + reg;
        if (grow >= NN) continue;
#pragma unroll
        for (int nb = 0; nb < 8; nb++) {
            const int col = nb * 16 + l15;
            float v = (acc[nb][reg] - mu[reg]) * rstd[reg] * gv[nb] + bbv[nb];
            hb[(size_t)grow * HID + col] = f2bf(fmaxf(v, 0.f));
        }
    }
}

// ---------------- dual GEMM (h@Wl -> xl bf16, h@Wr -> xr bf16), MFMA ---------
__global__ __launch_bounds__(256) void gemm_xlxr_mfma(
        const unsigned short* __restrict__ hb,
        const float4* __restrict__ wp,
        unsigned short* __restrict__ xl,
        unsigned short* __restrict__ xrb) {
    __shared__ s8v wlds[4096];                // 64 KB
    const int tid = threadIdx.x;
    const int wv = tid >> 6, lane = tid & 63;
    const int l15 = lane & 15, kseg = lane >> 4;
    const int row0 = blockIdx.x * 64 + wv * 16;
    const int arow = row0 + l15;
    const int r = (arow < NN) ? arow : 0;

    s8v afrag[4];
#pragma unroll
    for (int ks = 0; ks < 4; ks++)
        afrag[ks] = *(const s8v*)(hb + (size_t)r * HID + ks * 32 + kseg * 8);

#pragma unroll
    for (int i = 0; i < 16; i++) {
        const int idx = i * 256 + tid;
        ((float4*)wlds)[idx] = wp[idx];
    }
    __syncthreads();

    f4v accL[8], accR[8];
#pragma unroll
    for (int nb = 0; nb < 8; nb++) {
        accL[nb] = (f4v){0.f, 0.f, 0.f, 0.f};
        accR[nb] = (f4v){0.f, 0.f, 0.f, 0.f};
    }
#pragma unroll
    for (int ks = 0; ks < 4; ks++) {
#pragma unroll
        for (int nb = 0; nb < 8; nb++) {
            const s8v bL = wlds[(ks * 4 + kseg) * 128 + nb * 16 + l15];
            accL[nb] = __builtin_amdgcn_mfma_f32_16x16x32_bf16(afrag[ks], bL, accL[nb], 0, 0, 0);
            const s8v bR = wlds[2048 + (ks * 4 + kseg) * 128 + nb * 16 + l15];
            accR[nb] = __builtin_amdgcn_mfma_f32_16x16x32_bf16(afrag[ks], bR, accR[nb], 0, 0, 0);
        }
    }

    const int rbase = row0 + 4 * kseg;
#pragma unroll
    for (int reg = 0; reg < 4; reg++) {
        const int grow = rbase + reg;
        if (grow >= NN) continue;
#pragma unroll
        for (int nb = 0; nb < 8; nb++) {
            const int col = nb * 16 + l15;
            xl[(size_t)grow * HID + col]  = f2bf(accL[nb][reg]);
            xrb[(size_t)grow * HID + col] = f2bf(accR[nb][reg]);
        }
    }
}

// ---------------- CSR build (atomic-free scatter) ----------------
__global__ void dst_hist(const int* __restrict__ ei, int* __restrict__ cnt,
                         unsigned short* __restrict__ epos) {
    const long e = (long)blockIdx.x * 256 + threadIdx.x;
    if (e >= EP) return;
    const int d = (e < EE) ? ei[EE + e] : (int)(e - EE);
    epos[e] = (unsigned short)atomicAdd(&cnt[d], 1);
}

__global__ void scan_bsum(const int* __restrict__ cnt, int* __restrict__ bsum) {
    const int tid = threadIdx.x;
    const int i = blockIdx.x * 256 + tid;
    int v = (i < NN) ? cnt[i] : 0;
#pragma unroll
    for (int off = 1; off < 64; off <<= 1) v += __shfl_xor(v, off);
    __shared__ int ws[4];
    if ((tid & 63) == 0) ws[tid >> 6] = v;
    __syncthreads();
    if (tid == 0) bsum[blockIdx.x] = ws[0] + ws[1] + ws[2] + ws[3];
}

// local scan + self-computed block prefix
__global__ void scan_rowptr(const int* __restrict__ cnt,
                            const int* __restrict__ bsum,
                            int* __restrict__ rowptr) {
    const int tid = threadIdx.x;
    const int lane = tid & 63, wv = tid >> 6;
    __shared__ int ws[4];
    __shared__ int pref;

    {
        int v = (tid < blockIdx.x && tid < NB) ? bsum[tid] : 0;
#pragma unroll
        for (int off = 1; off < 64; off <<= 1) v += __shfl_xor(v, off);
        if (lane == 0) ws[wv] = v;
        __syncthreads();
        if (tid == 0) pref = ws[0] + ws[1] + ws[2] + ws[3];
        __syncthreads();
    }

    const int i = blockIdx.x * 256 + tid;
    const int v = (i < NN) ? cnt[i] : 0;
    int s = v;
#pragma unroll
    for (int off = 1; off < 64; off <<= 1) {
        const int u = __shfl_up(s, off);
        if (lane >= off) s += u;
    }
    __shared__ int wt[4];
    if (lane == 63) wt[wv] = s;
    __syncthreads();
    int add = pref;
    for (int w = 0; w < wv; w++) add += wt[w];
    const int excl = s + add - v;
    if (i < NN) rowptr[i] = excl;
    if (i == NN - 1) rowptr[NN] = excl + v;   // == EP
}

// atomic-free scatter: PRE-SHIFTED u32 byte offsets at precomputed positions
__global__ void csr_scatter(const int* __restrict__ ei,
                            const int* __restrict__ rowptr,
                            const unsigned short* __restrict__ epos,
                            int* __restrict__ esrcb) {
    const long e = (long)blockIdx.x * 256 + threadIdx.x;
    if (e >= EP) return;
    int s, d;
    if (e < EE) { s = ei[e]; d = ei[EE + e]; }
    else        { s = d = (int)(e - EE); }
    esrcb[rowptr[d] + epos[e]] = s * (HID * 2);   // byte offset into bf16 xl
}

// ---------------- fused GAT conv + LN + ELU + residual ----------------
// 4 nodes/wave: 16-lane group per node, lane holds 8 features.
// 4-deep gather pipeline + double-buffered offset refill + DPP quad reduce.
__global__ __launch_bounds__(256) void gat_ln(
        const unsigned short* __restrict__ xl,
        const unsigned short* __restrict__ xrb,
        const float* __restrict__ att,
        const int* __restrict__ rowptr,
        const int* __restrict__ esrcb,
        const float* __restrict__ g,
        const float* __restrict__ b,
        const unsigned short* __restrict__ hres,   // bf16 residual
        float* __restrict__ dest,                  // f32 out (last layer) or null
        unsigned short* __restrict__ destb) {      // bf16 h_next or null
    const int tid = threadIdx.x;
    const int lane = tid & 63;
    const int wv = tid >> 6;
    const int l16 = lane & 15;
    const int node = blockIdx.x * 16 + wv * 4 + (lane >> 4);   // grid*16 == NN
    const int f0 = l16 * 8;

    float xrv[8], a06[8], a04[8];
    {
        const uint4 xraw = *(const uint4*)(xrb + (size_t)node * HID + f0);
        unpack8(xraw, xrv);
        const float4 t0 = *(const float4*)(att + f0);
        const float4 t1 = *(const float4*)(att + f0 + 4);
        float av[8] = { t0.x, t0.y, t0.z, t0.w, t1.x, t1.y, t1.z, t1.w };
#pragma unroll
        for (int j = 0; j < 8; j++) {
            a06[j] = 0.6f * L2E * av[j];
            a04[j] = 0.4f * L2E * av[j];
        }
    }
    // hoist epilogue constants (latency overlap with edge loop)
    float gv[8], bv[8], hv[8];
    {
        const float4 g0 = *(const float4*)(g + f0);
        const float4 g1 = *(const float4*)(g + f0 + 4);
        gv[0]=g0.x; gv[1]=g0.y; gv[2]=g0.z; gv[3]=g0.w;
        gv[4]=g1.x; gv[5]=g1.y; gv[6]=g1.z; gv[7]=g1.w;
        const float4 b0 = *(const float4*)(b + f0);
        const float4 b1 = *(const float4*)(b + f0 + 4);
        bv[0]=b0.x; bv[1]=b0.y; bv[2]=b0.z; bv[3]=b0.w;
        bv[4]=b1.x; bv[5]=b1.y; bv[6]=b1.z; bv[7]=b1.w;
        const uint4 hraw = *(const uint4*)(hres + (size_t)node * HID + f0);
        unpack8(hraw, hv);
    }
    const int beg = rowptr[node];
    const int deg = rowptr[node + 1] - beg;            // >= 1
    int dmax = deg;
    dmax = max(dmax, __shfl_xor(dmax, 16));
    dmax = max(dmax, __shfl_xor(dmax, 32));            // max over the wave's 4 nodes

    const char* xlbase = (const char*)xl + f0 * 2;     // lane feature base (bytes)
    const int gb = lane & 48;                          // shfl base of this group

    float acc[8];
#pragma unroll
    for (int j = 0; j < 8; j++) acc[j] = 0.f;
    float z = 0.f;

    // double-buffered 16-deep offset windows (prefetched one window ahead)
    int sb_cur = (l16 < deg)      ? esrcb[beg + l16]      : 0;
    int sb_nxt = (16 + l16 < deg) ? esrcb[beg + 16 + l16] : 0;

#define PROCR(RAW, VALID) do {                                              \
        float m[8];                                                         \
        unpack8((RAW), m);                                                  \
        float v = 0.f;                                                      \
        _Pragma("unroll")                                                   \
        for (int j = 0; j < 8; j++) {                                       \
            const float tt = m[j] + xrv[j];                                 \
            v += tt * a06[j] + fabsf(tt) * a04[j];                          \
        }                                                                   \
        v = quad_sum(v);                /* head = 4 lanes, DPP */           \
        const float a = (VALID) ? __builtin_amdgcn_exp2f(v) : 0.f;          \
        z += a;                                                             \
        _Pragma("unroll")                                                   \
        for (int j = 0; j < 8; j++) acc[j] = fmaf(a, m[j], acc[j]);         \
    } while (0)

    for (int t = 0; t < dmax; t += 4) {
        if ((t & 15) == 0 && t) {                      // rotate windows
            sb_cur = sb_nxt;
            sb_nxt = (t + 16 + l16 < deg) ? esrcb[beg + t + 16 + l16] : 0;
        }
        const int o0 = __shfl(sb_cur, gb | ((t + 0) & 15));
        const int o1 = __shfl(sb_cur, gb | ((t + 1) & 15));
        const int o2 = __shfl(sb_cur, gb | ((t + 2) & 15));
        const int o3 = __shfl(sb_cur, gb | ((t + 3) & 15));
        // 4 independent loads in flight
        const uint4 r0 = *(const uint4*)(xlbase + o0);
        const uint4 r1 = *(const uint4*)(xlbase + o1);
        const uint4 r2 = *(const uint4*)(xlbase + o2);
        const uint4 r3 = *(const uint4*)(xlbase + o3);
        PROCR(r0, t + 0 < deg);
        PROCR(r1, t + 1 < deg);
        PROCR(r2, t + 2 < deg);
        PROCR(r3, t + 3 < deg);
    }
#undef PROCR

    // epilogue: alpha normalize + LN + ELU + residual (group-local)
    const float inv = 1.f / z;
    float o[8];
    float s1 = 0.f, s2 = 0.f;
#pragma unroll
    for (int j = 0; j < 8; j++) {
        o[j] = acc[j] * inv;
        s1 += o[j];
        s2 = fmaf(o[j], o[j], s2);
    }
#pragma unroll
    for (int off = 1; off < 16; off <<= 1) {
        s1 += __shfl_xor(s1, off);
        s2 += __shfl_xor(s2, off);
    }
    const float mu = s1 / (float)HID;
    const float rstd = rsqrtf(s2 / (float)HID - mu * mu + LN_EPS);

    float res[8];
#pragma unroll
    for (int j = 0; j < 8; j++) {
        float n = (o[j] - mu) * rstd * gv[j] + bv[j];
        n = (n > 0.f) ? n : (__builtin_amdgcn_exp2f(n * L2E) - 1.f);   // ELU
        res[j] = hv[j] + n;
    }
    if (dest) {
        float* dp = dest + (size_t)node * HID + f0;
        *(float4*)dp       = (float4){res[0], res[1], res[2], res[3]};
        *(float4*)(dp + 4) = (float4){res[4], res[5], res[6], res[7]};
    }
    if (destb) {
        unsigned short o16[8];
#pragma unroll
        for (int j = 0; j < 8; j++) o16[j] = f2bf(res[j]);
        *(uint4*)(destb + (size_t)node * HID + f0) = *(const uint4*)o16;
    }
}

extern "C" void kernel_launch(void* const* d_in, const int* in_sizes, int n_in,
                              void* d_out, int out_size, void* d_ws, size_t ws_size,
                              hipStream_t stream) {
    const float* x       = (const float*)d_in[0];
    const float* W_in    = (const float*)d_in[1];
    const float* b_in    = (const float*)d_in[2];
    const float* ln_in_g = (const float*)d_in[3];
    const float* ln_in_b = (const float*)d_in[4];
    const float* Wl      = (const float*)d_in[5];
    const float* Wr      = (const float*)d_in[6];
    const float* att     = (const float*)d_in[7];
    const float* ln_g    = (const float*)d_in[8];
    const float* ln_b    = (const float*)d_in[9];
    const int*   ei      = (const int*)d_in[10];
    float* out = (float*)d_out;

    unsigned short* hb  = (unsigned short*)d_ws;               // NN*128 bf16
    unsigned short* hb2 = hb  + (size_t)NN * HID;              // NN*128 bf16
    unsigned short* xlb = hb2 + (size_t)NN * HID;              // NN*128 bf16
    unsigned short* xrb = xlb + (size_t)NN * HID;              // NN*128 bf16
    float4* wp = (float4*)(xrb + (size_t)NN * HID);            // 12288 slots
    int* cnt    = (int*)(wp + 12288);                          // NN
    int* rowptr = cnt + NN;                                    // NN+1
    int* bsum   = rowptr + (NN + 1);                           // NB
    int* esrcb  = bsum + NB;                                   // EP i32 (byte offs)
    unsigned short* epos = (unsigned short*)(esrcb + EP);      // EP u16

    prep_weights<<<48, 256, 0, stream>>>(W_in, Wl, Wr, wp, cnt);

    const int eblocks = (EP + 255) / 256;
    dst_hist<<<eblocks, 256, 0, stream>>>(ei, cnt, epos);
    scan_bsum<<<NB, 256, 0, stream>>>(cnt, bsum);
    scan_rowptr<<<NB, 256, 0, stream>>>(cnt, bsum, rowptr);
    csr_scatter<<<eblocks, 256, 0, stream>>>(ei, rowptr, epos, esrcb);

    const int mblocks = (NN + 63) / 64;
    gemm_in_mfma<<<mblocks, 256, 0, stream>>>(x, wp, b_in, ln_in_g, ln_in_b, hb);

    for (int l = 0; l < 2; l++) {
        const unsigned short* hsrc = (l == 0) ? hb : hb2;
        gemm_xlxr_mfma<<<mblocks, 256, 0, stream>>>(hsrc, wp + 4096 + l * 4096, xlb, xrb);
        gat_ln<<<NN / 16, 256, 0, stream>>>(xlb, xrb, att + (size_t)l * HID,
                                            rowptr, esrcb,
                                            ln_g + (size_t)l * HID,
                                            ln_b + (size_t)l * HID,
                                            hsrc,
                                            (l == 1) ? out : (float*)nullptr,
                                            (l == 0) ? hb2 : (unsigned short*)nullptr);
    }
}